// Round 19
// baseline (144.986 us; speedup 1.0000x reference)
//
#include <hip/hip_runtime.h>
#include <hip/hip_fp8.h>

#define NFEAT 256
#define NHID 128
#define NCLASS 40
#define NNODES 50000
#define NEDGES 800000
#define BN_EPS 1e-5f
#define NBK 196          // buckets = dst>>8  (256 nodes each)
#define NBLK 100         // edge blocks of 8000
#define EPB 8000
#define NG1 3125         // gemm1 node-groups (16 nodes each)
#define G1L_BLOCKS 1024  // gemm blocks in fused launch (512 per half)

typedef __attribute__((ext_vector_type(4))) float f32x4;
typedef __attribute__((ext_vector_type(8))) short bf16x8;

__device__ inline ushort f2bf(float f) {          // RNE f32 -> bf16
    uint u = __float_as_uint(f);
    u += 0x7FFF + ((u >> 16) & 1);
    return (ushort)(u >> 16);
}
__device__ inline float bflo(uint v) { return __uint_as_float(v << 16); }
__device__ inline float bfhi(uint v) { return __uint_as_float(v & 0xFFFF0000u); }

__device__ inline uint pk_fp8x4(float a0, float a1, float a2, float a3) {
#if __has_builtin(__builtin_amdgcn_cvt_pk_fp8_f32)
    int u = 0;
    u = __builtin_amdgcn_cvt_pk_fp8_f32(a0, a1, u, false);
    u = __builtin_amdgcn_cvt_pk_fp8_f32(a2, a3, u, true);
    return (uint)u;
#else
    __hip_fp8_e4m3 q0(a0), q1(a1), q2(a2), q3(a3);
    return (uint)q0.__x | ((uint)q1.__x << 8) | ((uint)q2.__x << 16) | ((uint)q3.__x << 24);
#endif
}
__device__ inline float fp8lo(uint v) {
#if __has_builtin(__builtin_amdgcn_cvt_f32_fp8)
    return __builtin_amdgcn_cvt_f32_fp8((int)v, 0);
#else
    __hip_fp8_e4m3 q; q.__x = (__hip_fp8_storage_t)(v & 0xFF); return (float)q;
#endif
}
__device__ inline float fp8hi(uint v) {
#if __has_builtin(__builtin_amdgcn_cvt_f32_fp8)
    return __builtin_amdgcn_cvt_f32_fp8((int)v, 1);
#else
    __hip_fp8_e4m3 q; q.__x = (__hip_fp8_storage_t)((v >> 8) & 0xFF); return (float)q;
#endif
}

// ---------------- L1: W0 repack + stats-zero (blocks 0-15) + bucket count (16-115) ----------------
__global__ void k_prep(const float* __restrict__ W0, ushort* __restrict__ W0F,
                       const int* __restrict__ ei, int* __restrict__ bcnt,
                       float* __restrict__ stats, int* __restrict__ rowptr) {
    __shared__ int cnt[NBK];
    if (blockIdx.x < 16) {
        if (blockIdx.x == 0) {
            stats[threadIdx.x] = 0.f;                     // sums+sumsq (256 f)
            if (threadIdx.x == 0) rowptr[NNODES] = NEDGES;
        }
        const int t = blockIdx.x * 256 + threadIdx.x;     // 0..4095
        const int lane = t & 63;
        const int grp = t >> 6;                           // fi*8 + kc
        const int kc = grp & 7, fi = grp >> 3;
        const int n = fi * 16 + (lane & 15);
        const int k0 = kc * 32 + (lane >> 4) * 8;
        ushort v[8];
        #pragma unroll
        for (int j = 0; j < 8; ++j) v[j] = f2bf(W0[(k0 + j) * NHID + n]);
        uint4 u;
        u.x = (uint)v[0] | ((uint)v[1] << 16);
        u.y = (uint)v[2] | ((uint)v[3] << 16);
        u.z = (uint)v[4] | ((uint)v[5] << 16);
        u.w = (uint)v[6] | ((uint)v[7] << 16);
        *(uint4*)&W0F[(grp * 64 + lane) * 8] = u;
    } else {
        const int blk = blockIdx.x - 16;
        const int t = threadIdx.x;
        if (t < NBK) cnt[t] = 0;
        __syncthreads();
        const int base = blk * EPB;
        for (int i = t; i < EPB; i += 256)
            atomicAdd(&cnt[ei[NEDGES + base + i] >> 8], 1);
        __syncthreads();
        if (t < NBK) bcnt[blk * NBK + t] = cnt[t];
    }
}

// ---------------- L2: standalone scatter with own-scan offsets ----------------
__global__ void k_scatter(const int* __restrict__ ei, const int* __restrict__ bcnt,
                          uint* __restrict__ packed) {
    __shared__ int s_sc[256], s_cur[256];
    const int tid = threadIdx.x, blk = blockIdx.x;
    int tot = 0, pre = 0;
    if (tid < NBK) {
        for (int bb = 0; bb < NBLK; ++bb) {
            const int v = bcnt[bb * NBK + tid];
            tot += v;
            if (bb < blk) pre += v;
        }
    }
    s_sc[tid] = tot;
    __syncthreads();
    for (int o = 1; o < 256; o <<= 1) {
        const int v = (tid >= o) ? s_sc[tid - o] : 0;
        __syncthreads();
        s_sc[tid] += v;
        __syncthreads();
    }
    s_cur[tid] = (s_sc[tid] - tot) + pre;
    __syncthreads();
    const int base = blk * EPB;
    for (int i = tid; i < EPB; i += 256) {
        const int src = ei[base + i];
        const int dst = ei[NEDGES + base + i];
        const int pos = atomicAdd(&s_cur[dst >> 8], 1);
        packed[pos] = (uint)src | ((uint)(dst & 255) << 16);
    }
}

// ---------------- L3: bucket sort (blocks 0-195) ∥ GEMM1 w/ LDS-staged W0F half (196+) ----------------
__launch_bounds__(256)
__global__ void k_sort_gemm1(const uint* __restrict__ packed, const int* __restrict__ bcnt,
                             int* __restrict__ esrc, int* __restrict__ rowptr,
                             const float* __restrict__ x, const ushort* __restrict__ W0F,
                             uchar* __restrict__ h1) {
    __shared__ int s_cnt[256], s_sc[256], s_cur[256];
    __shared__ int s_seg[2];
    __shared__ __align__(16) uchar lds_w[32768];   // one W0F half
    if (blockIdx.x < NBK) {
        const int b = blockIdx.x, tid = threadIdx.x;
        int tot = 0;
        if (tid < NBK)
            for (int bb = 0; bb < NBLK; ++bb) tot += bcnt[bb * NBK + tid];
        s_sc[tid] = tot;
        __syncthreads();
        for (int o = 1; o < 256; o <<= 1) {
            const int v = (tid >= o) ? s_sc[tid - o] : 0;
            __syncthreads();
            s_sc[tid] += v;
            __syncthreads();
        }
        if (tid == b) { s_seg[0] = s_sc[b] - tot; s_seg[1] = s_sc[b]; }
        __syncthreads();
        const int nb = s_seg[0], ne = s_seg[1], n = ne - nb;
        s_cnt[tid] = 0;
        __syncthreads();
        for (int i = tid; i < n; i += 256)
            atomicAdd(&s_cnt[packed[nb + i] >> 16], 1);
        __syncthreads();
        const int v = s_cnt[tid];
        s_sc[tid] = v;
        __syncthreads();
        for (int o = 1; o < 256; o <<= 1) {
            const int tmp = (tid >= o) ? s_sc[tid - o] : 0;
            __syncthreads();
            s_sc[tid] += tmp;
            __syncthreads();
        }
        const int excl = s_sc[tid] - v;
        s_cur[tid] = excl;
        const int node = (b << 8) + tid;
        if (node < NNODES) rowptr[node] = nb + excl;
        __syncthreads();
        for (int i = tid; i < n; i += 256) {
            const uint p = packed[nb + i];
            const int pos = atomicAdd(&s_cur[p >> 16], 1);
            esrc[nb + pos] = (int)(p & 0xFFFFu);
        }
    } else {
        // ---- GEMM1: stage this half's 32 W0F fragments (32 KB) into LDS once ----
        const int gb = blockIdx.x - NBK;              // 0..1023
        const int half = gb & 1;
        const uchar* wsrc = (const uchar*)W0F + half * 32768;
        for (int i = threadIdx.x * 16; i < 32768; i += 256 * 16)
            *(uint4*)&lds_w[i] = *(const uint4*)&wsrc[i];
        __syncthreads();

        const int wv = threadIdx.x >> 6;
        const int lane = threadIdx.x & 63;
        const int laneoff = lane * 16;                // LDS byte offset within fragment

        for (int g = (gb >> 1) * 4 + wv; g < NG1; g += (G1L_BLOCKS / 2) * 4) {
            const int node = g * 16 + (lane & 15);
            const int nclamp = node < NNODES ? node : NNODES - 1;
            const float* xg = &x[(long)nclamp * NFEAT + (lane >> 4) * 8];

            float4 xa[8], xb[8];
            #pragma unroll
            for (int kc = 0; kc < 8; ++kc) {
                xa[kc] = *(const float4*)(xg + kc * 32);
                xb[kc] = *(const float4*)(xg + kc * 32 + 4);
            }
            bf16x8 xf[8];
            #pragma unroll
            for (int kc = 0; kc < 8; ++kc) {
                xf[kc][0]=(short)f2bf(xa[kc].x); xf[kc][1]=(short)f2bf(xa[kc].y);
                xf[kc][2]=(short)f2bf(xa[kc].z); xf[kc][3]=(short)f2bf(xa[kc].w);
                xf[kc][4]=(short)f2bf(xb[kc].x); xf[kc][5]=(short)f2bf(xb[kc].y);
                xf[kc][6]=(short)f2bf(xb[kc].z); xf[kc][7]=(short)f2bf(xb[kc].w);
            }
            f32x4 acc[4];
            #pragma unroll
            for (int f = 0; f < 4; ++f) acc[f] = (f32x4){0.f, 0.f, 0.f, 0.f};
            #pragma unroll
            for (int kc = 0; kc < 8; ++kc) {
                #pragma unroll
                for (int f = 0; f < 4; ++f) {
                    const bf16x8 wf =
                        *(const bf16x8*)&lds_w[((f * 8 + kc) * 64) * 16 + laneoff];
                    acc[f] = __builtin_amdgcn_mfma_f32_16x16x32_bf16(wf, xf[kc], acc[f], 0, 0, 0);
                }
            }
            if (node < NNODES) {
                const int nq = (lane >> 4) * 4;
                uchar* hp = &h1[(long)node * NHID + half * 64 + nq];
                #pragma unroll
                for (int f = 0; f < 4; ++f)
                    *(uint*)&hp[f * 16] = pk_fp8x4(acc[f][0], acc[f][1], acc[f][2], acc[f][3]);
            }
        }
    }
}

// ---------------- L4: gather1 (one wave per node): agg1bf[n] = bf16(b0 + sum h1[src]) ----------------
__launch_bounds__(256)
__global__ void k_gather1(const int* __restrict__ rowptr, const int* __restrict__ esrc,
                          const uchar* __restrict__ h1, const float* __restrict__ b0,
                          ushort* __restrict__ agg1bf) {
    const int w = (blockIdx.x * blockDim.x + threadIdx.x) >> 6;
    const int lane = threadIdx.x & 63;
    if (w >= NNODES) return;
    const int beg = rowptr[w], end = rowptr[w + 1];
    const int f = lane * 2;
    float2 acc = *(const float2*)&b0[f];
    int i = beg;
    for (; i + 7 < end; i += 8) {
        uint v[8];
        #pragma unroll
        for (int j = 0; j < 8; ++j)
            v[j] = (uint)*(const ushort*)&h1[(long)esrc[i + j] * NHID + f];
        #pragma unroll
        for (int j = 0; j < 8; ++j) { acc.x += fp8lo(v[j]); acc.y += fp8hi(v[j]); }
    }
    for (; i < end; ++i) {
        const uint v = (uint)*(const ushort*)&h1[(long)esrc[i] * NHID + f];
        acc.x += fp8lo(v); acc.y += fp8hi(v);
    }
    const uint u = (uint)f2bf(acc.x) | ((uint)f2bf(acc.y) << 16);
    *(uint*)&agg1bf[(long)w * NHID + f] = u;
}

// ---------------- L5: BN stats (bf16 in, 12.8 MB) ----------------
__global__ void k_bnstats(const ushort* __restrict__ agg1bf,
                          float* __restrict__ sums, float* __restrict__ sumsq) {
    __shared__ float sd[256 * 8], sd2[256 * 8];
    const int t = threadIdx.x;
    const int c8 = (t & 15) * 8;
    const int rr = t >> 4;
    float s[8] = {}, q[8] = {};
    for (int r = blockIdx.x * 16 + rr; r < NNODES; r += gridDim.x * 16) {
        const uint4 u = *(const uint4*)&agg1bf[(long)r * NHID + c8];
        const uint uu[4] = {u.x, u.y, u.z, u.w};
        #pragma unroll
        for (int j = 0; j < 4; ++j) {
            const float a0 = bflo(uu[j]), a1 = bfhi(uu[j]);
            s[2 * j] += a0; s[2 * j + 1] += a1;
            q[2 * j] += a0 * a0; q[2 * j + 1] += a1 * a1;
        }
    }
    #pragma unroll
    for (int j = 0; j < 8; ++j) { sd[t * 8 + j] = s[j]; sd2[t * 8 + j] = q[j]; }
    __syncthreads();
    if (t < 128) {
        const int g = t >> 3, j = t & 7;
        float ss = 0.f, qq = 0.f;
        #pragma unroll
        for (int r = 0; r < 16; ++r) {
            ss += sd[(r * 16 + g) * 8 + j];
            qq += sd2[(r * 16 + g) * 8 + j];
        }
        atomicAdd(&sums[g * 8 + j], ss);
        atomicAdd(&sumsq[g * 8 + j], qq);
    }
}

// ---------------- L6: GEMM2 (bf16 agg in) with inlined BN-final + ReLU ----------------
__launch_bounds__(256)
__global__ void k_gemm2(const ushort* __restrict__ agg1bf, const float* __restrict__ W1,
                        const float* __restrict__ sums, const float* __restrict__ sumsq,
                        const float* __restrict__ gamma, const float* __restrict__ beta,
                        ushort* __restrict__ h2) {
    __shared__ float xs[64 * 132];
    __shared__ float wt[40 * 132];
    __shared__ float s_scale[128], s_shift[128];
    const int t = threadIdx.x;
    const int base = blockIdx.x * 64;

    if (t < NHID) {
        const float mu = sums[t] * (1.f / NNODES);
        float var = sumsq[t] * (1.f / NNODES) - mu * mu;
        var = fmaxf(var, 0.f);
        const float sc = gamma[t] * rsqrtf(var + BN_EPS);
        s_scale[t] = sc;
        s_shift[t] = beta[t] - mu * sc;
    }
    for (int idx = t; idx < NHID * NCLASS; idx += 256) {
        const int c = idx / NCLASS, j = idx % NCLASS;
        wt[j * 132 + c] = W1[idx];
    }
    __syncthreads();
    {
        const int cc = (t & 15) * 8;
        const int rb = t >> 4;
        #pragma unroll
        for (int p = 0; p < 4; ++p) {
            const int row = p * 16 + rb;
            const int g = base + row;
            uint4 u = make_uint4(0u, 0u, 0u, 0u);
            if (g < NNODES) u = *(const uint4*)&agg1bf[(long)g * NHID + cc];
            const uint uu[4] = {u.x, u.y, u.z, u.w};
            #pragma unroll
            for (int q = 0; q < 4; ++q) {
                const int c0 = cc + q * 2;
                const float a0 = bflo(uu[q]), a1 = bfhi(uu[q]);
                xs[row * 132 + c0]     = fmaxf(a0 * s_scale[c0]     + s_shift[c0],     0.f);
                xs[row * 132 + c0 + 1] = fmaxf(a1 * s_scale[c0 + 1] + s_shift[c0 + 1], 0.f);
            }
        }
    }
    __syncthreads();

    const int node = t >> 2;
    const int j0 = (t & 3) * 10;
    float acc[10] = {};
    for (int c4 = 0; c4 < 32; ++c4) {
        const int c = c4 * 4;
        const float4 a = *(const float4*)&xs[node * 132 + c];
        #pragma unroll
        for (int jj = 0; jj < 10; ++jj) {
            const float4 wv = *(const float4*)&wt[(j0 + jj) * 132 + c];
            acc[jj] += a.x * wv.x + a.y * wv.y + a.z * wv.z + a.w * wv.w;
        }
    }
    const int g = base + node;
    if (g < NNODES) {
        #pragma unroll
        for (int p = 0; p < 5; ++p) {
            uint u = (uint)f2bf(acc[2 * p]) | ((uint)f2bf(acc[2 * p + 1]) << 16);
            *(uint*)&h2[(long)g * NCLASS + j0 + 2 * p] = u;
        }
    }
}

// ---------------- L7: gather2: out[n] = b1 + sum h2[src] (12 nodes/block) ----------------
__launch_bounds__(256)
__global__ void k_gather2(const int* __restrict__ rowptr, const int* __restrict__ esrc,
                          const ushort* __restrict__ h2, const float* __restrict__ b1,
                          float* __restrict__ out) {
    const int t = threadIdx.x;
    if (t >= 240) return;
    const int node = blockIdx.x * 12 + t / 20;
    if (node >= NNODES) return;
    const int f = (t % 20) * 2;
    const int beg = rowptr[node], end = rowptr[node + 1];
    float2 acc = make_float2(b1[f], b1[f + 1]);
    int i = beg;
    for (; i + 3 < end; i += 4) {
        const uint v0 = *(const uint*)&h2[(long)esrc[i]     * NCLASS + f];
        const uint v1 = *(const uint*)&h2[(long)esrc[i + 1] * NCLASS + f];
        const uint v2 = *(const uint*)&h2[(long)esrc[i + 2] * NCLASS + f];
        const uint v3 = *(const uint*)&h2[(long)esrc[i + 3] * NCLASS + f];
        acc.x += (bflo(v0) + bflo(v1)) + (bflo(v2) + bflo(v3));
        acc.y += (bfhi(v0) + bfhi(v1)) + (bfhi(v2) + bfhi(v3));
    }
    for (; i < end; ++i) {
        const uint v = *(const uint*)&h2[(long)esrc[i] * NCLASS + f];
        acc.x += bflo(v); acc.y += bfhi(v);
    }
    *(float2*)&out[(long)node * NCLASS + f] = acc;
}

extern "C" void kernel_launch(void* const* d_in, const int* in_sizes, int n_in,
                              void* d_out, int out_size, void* d_ws, size_t ws_size,
                              hipStream_t stream) {
    const float* x      = (const float*)d_in[0];
    const int*   ei     = (const int*)d_in[1];
    const float* W0     = (const float*)d_in[2];
    const float* b0     = (const float*)d_in[3];
    const float* gamma0 = (const float*)d_in[4];
    const float* beta0  = (const float*)d_in[5];
    const float* W1     = (const float*)d_in[6];
    const float* b1     = (const float*)d_in[7];
    float* out = (float*)d_out;

    char* ws = (char*)d_ws;
    float* sums  = (float*)ws;                 // 128 f
    float* sumsq = sums + 128;                 // 128 f (stats = 256 f contiguous)
    int* wsI     = (int*)(ws + 4096);
    int* rowptr  = wsI;                        // 50001 (pad 50048)
    int* esrc    = wsI + 50048;                // 800000
    int* bcnt    = wsI + 850048;               // 19600 (pad 19648)
    ushort* W0F  = (ushort*)(ws + 3563520);    // 64 KB fragment-major
    uchar* h1    = (uchar*)(ws + 3629056);     // 50000*128 fp8 = 6.4 MB
    ushort* agg1bf = (ushort*)(ws + 16429056); // 50000*128 bf16 = 12.8 MB
    uint* packed = (uint*)agg1bf;              // 3.2 MB, dead before gather1
    ushort* h2   = (ushort*)h1;                // 4 MB, h1 region dead after gather1

    k_prep<<<16 + NBLK, 256, 0, stream>>>(W0, W0F, ei, bcnt, sums, rowptr);
    k_scatter<<<NBLK, 256, 0, stream>>>(ei, bcnt, packed);
    k_sort_gemm1<<<NBK + G1L_BLOCKS, 256, 0, stream>>>(packed, bcnt, esrc, rowptr, x, W0F, h1);
    k_gather1<<<(NNODES * 64 + 255) / 256, 256, 0, stream>>>(rowptr, esrc, h1, b0, agg1bf);
    k_bnstats<<<256, 256, 0, stream>>>(agg1bf, sums, sumsq);
    k_gemm2<<<(NNODES + 63) / 64, 256, 0, stream>>>(agg1bf, W1, sums, sumsq, gamma0, beta0, h2);
    k_gather2<<<(NNODES + 11) / 12, 256, 0, stream>>>(rowptr, esrc, h2, b1, out);
}

// Round 20
// 142.480 us; speedup vs baseline: 1.0176x; 1.0176x over previous
//
#include <hip/hip_runtime.h>
#include <hip/hip_fp8.h>

#define NFEAT 256
#define NHID 128
#define NCLASS 40
#define NNODES 50000
#define NEDGES 800000
#define BN_EPS 1e-5f
#define NBK 196          // buckets = dst>>8  (256 nodes each)
#define NBLK 100         // edge blocks of 8000
#define EPB 8000
#define NW1 6250         // gemm1 wave-tasks: 3125 node-groups x 2 hid-halves
#define G1R_BLOCKS 512
#define G1R_WAVES (G1R_BLOCKS * 4)   // 2048 waves, ~3 tasks each

typedef __attribute__((ext_vector_type(4))) float f32x4;
typedef __attribute__((ext_vector_type(8))) short bf16x8;

__device__ inline ushort f2bf(float f) {          // RNE f32 -> bf16
    uint u = __float_as_uint(f);
    u += 0x7FFF + ((u >> 16) & 1);
    return (ushort)(u >> 16);
}
__device__ inline float bflo(uint v) { return __uint_as_float(v << 16); }
__device__ inline float bfhi(uint v) { return __uint_as_float(v & 0xFFFF0000u); }

__device__ inline uint pk_fp8x4(float a0, float a1, float a2, float a3) {
#if __has_builtin(__builtin_amdgcn_cvt_pk_fp8_f32)
    int u = 0;
    u = __builtin_amdgcn_cvt_pk_fp8_f32(a0, a1, u, false);
    u = __builtin_amdgcn_cvt_pk_fp8_f32(a2, a3, u, true);
    return (uint)u;
#else
    __hip_fp8_e4m3 q0(a0), q1(a1), q2(a2), q3(a3);
    return (uint)q0.__x | ((uint)q1.__x << 8) | ((uint)q2.__x << 16) | ((uint)q3.__x << 24);
#endif
}
__device__ inline float fp8lo(uint v) {
#if __has_builtin(__builtin_amdgcn_cvt_f32_fp8)
    return __builtin_amdgcn_cvt_f32_fp8((int)v, 0);
#else
    __hip_fp8_e4m3 q; q.__x = (__hip_fp8_storage_t)(v & 0xFF); return (float)q;
#endif
}
__device__ inline float fp8hi(uint v) {
#if __has_builtin(__builtin_amdgcn_cvt_f32_fp8)
    return __builtin_amdgcn_cvt_f32_fp8((int)v, 1);
#else
    __hip_fp8_e4m3 q; q.__x = (__hip_fp8_storage_t)((v >> 8) & 0xFF); return (float)q;
#endif
}

// ---------------- L1: W0 repack + stats-zero (blocks 0-15) + bucket count (16-115) ----------------
__global__ void k_prep(const float* __restrict__ W0, ushort* __restrict__ W0F,
                       const int* __restrict__ ei, int* __restrict__ bcnt,
                       float* __restrict__ stats, int* __restrict__ rowptr) {
    __shared__ int cnt[NBK];
    if (blockIdx.x < 16) {
        if (blockIdx.x == 0) {
            stats[threadIdx.x] = 0.f;                     // sums+sumsq (256 f)
            if (threadIdx.x == 0) rowptr[NNODES] = NEDGES;
        }
        const int t = blockIdx.x * 256 + threadIdx.x;     // 0..4095
        const int lane = t & 63;
        const int grp = t >> 6;                           // fi*8 + kc
        const int kc = grp & 7, fi = grp >> 3;
        const int n = fi * 16 + (lane & 15);
        const int k0 = kc * 32 + (lane >> 4) * 8;
        ushort v[8];
        #pragma unroll
        for (int j = 0; j < 8; ++j) v[j] = f2bf(W0[(k0 + j) * NHID + n]);
        uint4 u;
        u.x = (uint)v[0] | ((uint)v[1] << 16);
        u.y = (uint)v[2] | ((uint)v[3] << 16);
        u.z = (uint)v[4] | ((uint)v[5] << 16);
        u.w = (uint)v[6] | ((uint)v[7] << 16);
        *(uint4*)&W0F[(grp * 64 + lane) * 8] = u;
    } else {
        const int blk = blockIdx.x - 16;
        const int t = threadIdx.x;
        if (t < NBK) cnt[t] = 0;
        __syncthreads();
        const int base = blk * EPB;
        for (int i = t; i < EPB; i += 256)
            atomicAdd(&cnt[ei[NEDGES + base + i] >> 8], 1);
        __syncthreads();
        if (t < NBK) bcnt[blk * NBK + t] = cnt[t];
    }
}

// ---------------- L2: standalone scatter with own-scan offsets ----------------
__global__ void k_scatter(const int* __restrict__ ei, const int* __restrict__ bcnt,
                          uint* __restrict__ packed) {
    __shared__ int s_sc[256], s_cur[256];
    const int tid = threadIdx.x, blk = blockIdx.x;
    int tot = 0, pre = 0;
    if (tid < NBK) {
        for (int bb = 0; bb < NBLK; ++bb) {
            const int v = bcnt[bb * NBK + tid];
            tot += v;
            if (bb < blk) pre += v;
        }
    }
    s_sc[tid] = tot;
    __syncthreads();
    for (int o = 1; o < 256; o <<= 1) {
        const int v = (tid >= o) ? s_sc[tid - o] : 0;
        __syncthreads();
        s_sc[tid] += v;
        __syncthreads();
    }
    s_cur[tid] = (s_sc[tid] - tot) + pre;
    __syncthreads();
    const int base = blk * EPB;
    for (int i = tid; i < EPB; i += 256) {
        const int src = ei[base + i];
        const int dst = ei[NEDGES + base + i];
        const int pos = atomicAdd(&s_cur[dst >> 8], 1);
        packed[pos] = (uint)src | ((uint)(dst & 255) << 16);
    }
}

// ---------------- L3: bucket sort (blocks 0-195) ∥ GEMM1 w/ register W0F (196+) ----------------
__launch_bounds__(256)
__global__ void k_sort_gemm1(const uint* __restrict__ packed, const int* __restrict__ bcnt,
                             int* __restrict__ esrc, int* __restrict__ rowptr,
                             const float* __restrict__ x, const ushort* __restrict__ W0F,
                             uchar* __restrict__ h1) {
    __shared__ int s_cnt[256], s_sc[256], s_cur[256];
    __shared__ int s_seg[2];
    if (blockIdx.x < NBK) {
        const int b = blockIdx.x, tid = threadIdx.x;
        int tot = 0;
        if (tid < NBK)
            for (int bb = 0; bb < NBLK; ++bb) tot += bcnt[bb * NBK + tid];
        s_sc[tid] = tot;
        __syncthreads();
        for (int o = 1; o < 256; o <<= 1) {
            const int v = (tid >= o) ? s_sc[tid - o] : 0;
            __syncthreads();
            s_sc[tid] += v;
            __syncthreads();
        }
        if (tid == b) { s_seg[0] = s_sc[b] - tot; s_seg[1] = s_sc[b]; }
        __syncthreads();
        const int nb = s_seg[0], ne = s_seg[1], n = ne - nb;
        s_cnt[tid] = 0;
        __syncthreads();
        for (int i = tid; i < n; i += 256)
            atomicAdd(&s_cnt[packed[nb + i] >> 16], 1);
        __syncthreads();
        const int v = s_cnt[tid];
        s_sc[tid] = v;
        __syncthreads();
        for (int o = 1; o < 256; o <<= 1) {
            const int tmp = (tid >= o) ? s_sc[tid - o] : 0;
            __syncthreads();
            s_sc[tid] += tmp;
            __syncthreads();
        }
        const int excl = s_sc[tid] - v;
        s_cur[tid] = excl;
        const int node = (b << 8) + tid;
        if (node < NNODES) rowptr[node] = nb + excl;
        __syncthreads();
        for (int i = tid; i < n; i += 256) {
            const uint p = packed[nb + i];
            const int pos = atomicAdd(&s_cur[p >> 16], 1);
            esrc[nb + pos] = (int)(p & 0xFFFFu);
        }
    } else {
        // GEMM1: W0F half-fragments held in registers across ~3 node-group tasks.
        const int wv = threadIdx.x >> 6;
        const int lane = threadIdx.x & 63;
        const int W = (blockIdx.x - NBK) * 4 + wv;       // 0..2047
        const int half = W & 1;                           // task parity preserved (+2048)
        const ushort* wbase = &W0F[(size_t)lane * 8];

        bf16x8 wf[32];                                    // this half's fragments
        #pragma unroll
        for (int fi = 0; fi < 4; ++fi)
            #pragma unroll
            for (int kc = 0; kc < 8; ++kc)
                wf[fi * 8 + kc] =
                    *(const bf16x8*)&wbase[(size_t)(((half * 4 + fi) * 8 + kc) * 64) * 8];

        for (int task = W; task < NW1; task += G1R_WAVES) {
            const int g = task >> 1;
            const int node = g * 16 + (lane & 15);
            const int nclamp = node < NNODES ? node : NNODES - 1;
            const float* xg = &x[(long)nclamp * NFEAT + (lane >> 4) * 8];

            float4 xa[8], xb[8];
            #pragma unroll
            for (int kc = 0; kc < 8; ++kc) {
                xa[kc] = *(const float4*)(xg + kc * 32);
                xb[kc] = *(const float4*)(xg + kc * 32 + 4);
            }
            bf16x8 xf[8];
            #pragma unroll
            for (int kc = 0; kc < 8; ++kc) {
                xf[kc][0]=(short)f2bf(xa[kc].x); xf[kc][1]=(short)f2bf(xa[kc].y);
                xf[kc][2]=(short)f2bf(xa[kc].z); xf[kc][3]=(short)f2bf(xa[kc].w);
                xf[kc][4]=(short)f2bf(xb[kc].x); xf[kc][5]=(short)f2bf(xb[kc].y);
                xf[kc][6]=(short)f2bf(xb[kc].z); xf[kc][7]=(short)f2bf(xb[kc].w);
            }
            f32x4 acc[4];
            #pragma unroll
            for (int f = 0; f < 4; ++f) acc[f] = (f32x4){0.f, 0.f, 0.f, 0.f};
            #pragma unroll
            for (int kc = 0; kc < 8; ++kc)
                #pragma unroll
                for (int f = 0; f < 4; ++f)
                    acc[f] = __builtin_amdgcn_mfma_f32_16x16x32_bf16(wf[f * 8 + kc], xf[kc],
                                                                     acc[f], 0, 0, 0);
            if (node < NNODES) {
                const int nq = (lane >> 4) * 4;
                uchar* hp = &h1[(long)node * NHID + half * 64 + nq];
                #pragma unroll
                for (int f = 0; f < 4; ++f)
                    *(uint*)&hp[f * 16] = pk_fp8x4(acc[f][0], acc[f][1], acc[f][2], acc[f][3]);
            }
        }
    }
}

// ---------------- L4: gather1 (one wave per node): agg1bf[n] = bf16(b0 + sum h1[src]) ----------------
__launch_bounds__(256)
__global__ void k_gather1(const int* __restrict__ rowptr, const int* __restrict__ esrc,
                          const uchar* __restrict__ h1, const float* __restrict__ b0,
                          ushort* __restrict__ agg1bf) {
    const int w = (blockIdx.x * blockDim.x + threadIdx.x) >> 6;
    const int lane = threadIdx.x & 63;
    if (w >= NNODES) return;
    const int beg = rowptr[w], end = rowptr[w + 1];
    const int f = lane * 2;
    float2 acc = *(const float2*)&b0[f];
    int i = beg;
    for (; i + 7 < end; i += 8) {
        uint v[8];
        #pragma unroll
        for (int j = 0; j < 8; ++j)
            v[j] = (uint)*(const ushort*)&h1[(long)esrc[i + j] * NHID + f];
        #pragma unroll
        for (int j = 0; j < 8; ++j) { acc.x += fp8lo(v[j]); acc.y += fp8hi(v[j]); }
    }
    for (; i < end; ++i) {
        const uint v = (uint)*(const ushort*)&h1[(long)esrc[i] * NHID + f];
        acc.x += fp8lo(v); acc.y += fp8hi(v);
    }
    const uint u = (uint)f2bf(acc.x) | ((uint)f2bf(acc.y) << 16);
    *(uint*)&agg1bf[(long)w * NHID + f] = u;
}

// ---------------- L5: BN stats (bf16 in, 12.8 MB) ----------------
__global__ void k_bnstats(const ushort* __restrict__ agg1bf,
                          float* __restrict__ sums, float* __restrict__ sumsq) {
    __shared__ float sd[256 * 8], sd2[256 * 8];
    const int t = threadIdx.x;
    const int c8 = (t & 15) * 8;
    const int rr = t >> 4;
    float s[8] = {}, q[8] = {};
    for (int r = blockIdx.x * 16 + rr; r < NNODES; r += gridDim.x * 16) {
        const uint4 u = *(const uint4*)&agg1bf[(long)r * NHID + c8];
        const uint uu[4] = {u.x, u.y, u.z, u.w};
        #pragma unroll
        for (int j = 0; j < 4; ++j) {
            const float a0 = bflo(uu[j]), a1 = bfhi(uu[j]);
            s[2 * j] += a0; s[2 * j + 1] += a1;
            q[2 * j] += a0 * a0; q[2 * j + 1] += a1 * a1;
        }
    }
    #pragma unroll
    for (int j = 0; j < 8; ++j) { sd[t * 8 + j] = s[j]; sd2[t * 8 + j] = q[j]; }
    __syncthreads();
    if (t < 128) {
        const int g = t >> 3, j = t & 7;
        float ss = 0.f, qq = 0.f;
        #pragma unroll
        for (int r = 0; r < 16; ++r) {
            ss += sd[(r * 16 + g) * 8 + j];
            qq += sd2[(r * 16 + g) * 8 + j];
        }
        atomicAdd(&sums[g * 8 + j], ss);
        atomicAdd(&sumsq[g * 8 + j], qq);
    }
}

// ---------------- L6: GEMM2 (bf16 agg in) with inlined BN-final + ReLU ----------------
__launch_bounds__(256)
__global__ void k_gemm2(const ushort* __restrict__ agg1bf, const float* __restrict__ W1,
                        const float* __restrict__ sums, const float* __restrict__ sumsq,
                        const float* __restrict__ gamma, const float* __restrict__ beta,
                        ushort* __restrict__ h2) {
    __shared__ float xs[64 * 132];
    __shared__ float wt[40 * 132];
    __shared__ float s_scale[128], s_shift[128];
    const int t = threadIdx.x;
    const int base = blockIdx.x * 64;

    if (t < NHID) {
        const float mu = sums[t] * (1.f / NNODES);
        float var = sumsq[t] * (1.f / NNODES) - mu * mu;
        var = fmaxf(var, 0.f);
        const float sc = gamma[t] * rsqrtf(var + BN_EPS);
        s_scale[t] = sc;
        s_shift[t] = beta[t] - mu * sc;
    }
    for (int idx = t; idx < NHID * NCLASS; idx += 256) {
        const int c = idx / NCLASS, j = idx % NCLASS;
        wt[j * 132 + c] = W1[idx];
    }
    __syncthreads();
    {
        const int cc = (t & 15) * 8;
        const int rb = t >> 4;
        #pragma unroll
        for (int p = 0; p < 4; ++p) {
            const int row = p * 16 + rb;
            const int g = base + row;
            uint4 u = make_uint4(0u, 0u, 0u, 0u);
            if (g < NNODES) u = *(const uint4*)&agg1bf[(long)g * NHID + cc];
            const uint uu[4] = {u.x, u.y, u.z, u.w};
            #pragma unroll
            for (int q = 0; q < 4; ++q) {
                const int c0 = cc + q * 2;
                const float a0 = bflo(uu[q]), a1 = bfhi(uu[q]);
                xs[row * 132 + c0]     = fmaxf(a0 * s_scale[c0]     + s_shift[c0],     0.f);
                xs[row * 132 + c0 + 1] = fmaxf(a1 * s_scale[c0 + 1] + s_shift[c0 + 1], 0.f);
            }
        }
    }
    __syncthreads();

    const int node = t >> 2;
    const int j0 = (t & 3) * 10;
    float acc[10] = {};
    for (int c4 = 0; c4 < 32; ++c4) {
        const int c = c4 * 4;
        const float4 a = *(const float4*)&xs[node * 132 + c];
        #pragma unroll
        for (int jj = 0; jj < 10; ++jj) {
            const float4 wv = *(const float4*)&wt[(j0 + jj) * 132 + c];
            acc[jj] += a.x * wv.x + a.y * wv.y + a.z * wv.z + a.w * wv.w;
        }
    }
    const int g = base + node;
    if (g < NNODES) {
        #pragma unroll
        for (int p = 0; p < 5; ++p) {
            uint u = (uint)f2bf(acc[2 * p]) | ((uint)f2bf(acc[2 * p + 1]) << 16);
            *(uint*)&h2[(long)g * NCLASS + j0 + 2 * p] = u;
        }
    }
}

// ---------------- L7: gather2: out[n] = b1 + sum h2[src] (12 nodes/block) ----------------
__launch_bounds__(256)
__global__ void k_gather2(const int* __restrict__ rowptr, const int* __restrict__ esrc,
                          const ushort* __restrict__ h2, const float* __restrict__ b1,
                          float* __restrict__ out) {
    const int t = threadIdx.x;
    if (t >= 240) return;
    const int node = blockIdx.x * 12 + t / 20;
    if (node >= NNODES) return;
    const int f = (t % 20) * 2;
    const int beg = rowptr[node], end = rowptr[node + 1];
    float2 acc = make_float2(b1[f], b1[f + 1]);
    int i = beg;
    for (; i + 3 < end; i += 4) {
        const uint v0 = *(const uint*)&h2[(long)esrc[i]     * NCLASS + f];
        const uint v1 = *(const uint*)&h2[(long)esrc[i + 1] * NCLASS + f];
        const uint v2 = *(const uint*)&h2[(long)esrc[i + 2] * NCLASS + f];
        const uint v3 = *(const uint*)&h2[(long)esrc[i + 3] * NCLASS + f];
        acc.x += (bflo(v0) + bflo(v1)) + (bflo(v2) + bflo(v3));
        acc.y += (bfhi(v0) + bfhi(v1)) + (bfhi(v2) + bfhi(v3));
    }
    for (; i < end; ++i) {
        const uint v = *(const uint*)&h2[(long)esrc[i] * NCLASS + f];
        acc.x += bflo(v); acc.y += bfhi(v);
    }
    *(float2*)&out[(long)node * NCLASS + f] = acc;
}

extern "C" void kernel_launch(void* const* d_in, const int* in_sizes, int n_in,
                              void* d_out, int out_size, void* d_ws, size_t ws_size,
                              hipStream_t stream) {
    const float* x      = (const float*)d_in[0];
    const int*   ei     = (const int*)d_in[1];
    const float* W0     = (const float*)d_in[2];
    const float* b0     = (const float*)d_in[3];
    const float* gamma0 = (const float*)d_in[4];
    const float* beta0  = (const float*)d_in[5];
    const float* W1     = (const float*)d_in[6];
    const float* b1     = (const float*)d_in[7];
    float* out = (float*)d_out;

    char* ws = (char*)d_ws;
    float* sums  = (float*)ws;                 // 128 f
    float* sumsq = sums + 128;                 // 128 f (stats = 256 f contiguous)
    int* wsI     = (int*)(ws + 4096);
    int* rowptr  = wsI;                        // 50001 (pad 50048)
    int* esrc    = wsI + 50048;                // 800000
    int* bcnt    = wsI + 850048;               // 19600 (pad 19648)
    ushort* W0F  = (ushort*)(ws + 3563520);    // 64 KB fragment-major
    uchar* h1    = (uchar*)(ws + 3629056);     // 50000*128 fp8 = 6.4 MB
    ushort* agg1bf = (ushort*)(ws + 16429056); // 50000*128 bf16 = 12.8 MB
    uint* packed = (uint*)agg1bf;              // 3.2 MB, dead before gather1
    ushort* h2   = (ushort*)h1;                // 4 MB, h1 region dead after gather1

    k_prep<<<16 + NBLK, 256, 0, stream>>>(W0, W0F, ei, bcnt, sums, rowptr);
    k_scatter<<<NBLK, 256, 0, stream>>>(ei, bcnt, packed);
    k_sort_gemm1<<<NBK + G1R_BLOCKS, 256, 0, stream>>>(packed, bcnt, esrc, rowptr, x, W0F, h1);
    k_gather1<<<(NNODES * 64 + 255) / 256, 256, 0, stream>>>(rowptr, esrc, h1, b0, agg1bf);
    k_bnstats<<<256, 256, 0, stream>>>(agg1bf, sums, sumsq);
    k_gemm2<<<(NNODES + 63) / 64, 256, 0, stream>>>(agg1bf, W1, sums, sumsq, gamma0, beta0, h2);
    k_gather2<<<(NNODES + 11) / 12, 256, 0, stream>>>(rowptr, esrc, h2, b1, out);
}